// Round 10
// baseline (212.551 us; speedup 1.0000x reference)
//
#include <hip/hip_runtime.h>

typedef unsigned short u16;
typedef unsigned int   u32;
typedef __bf16 bf16x8 __attribute__((ext_vector_type(8)));
typedef float  f32x4  __attribute__((ext_vector_type(4)));

__device__ __forceinline__ u16 f2bf(float f){
  u32 u = __float_as_uint(f);
  return (u16)((u + 0x7FFFu + ((u >> 16) & 1u)) >> 16);  // RNE
}
__device__ __forceinline__ float bf2f(u16 h){ return __uint_as_float(((u32)h) << 16); }

// ---------------- workspace layout (bytes) ----------------
#define WS_A1    0u          // A1 LINEAR [384][256] bf16                196608
#define WS_WM0   196608u     // Wm0 wimg [256][512]  (BN=256,nK=8)      262144
#define WS_WM1   458752u     // Wm1 wimg [256][1024] (BN=256,nK=16)     524288
#define WS_WDVC  983040u     // Wdvc = 0.5*Wdet@Wv@Wc1 linear [256][128] bf16  65536
#define WS_C1    1048576u    // c1[384] f32
#define WS_B3    1050112u    // b3[256] f32
#define WS_BM0   1051136u
#define WS_BM1   1052160u
#define WS_T     1053184u    // T[128][256] f32 (Wq@Wc2)
#define WS_U     1184256u    // u[128] f32
#define WS_MR    1184768u    // M_r[128][256] f32 (0.5*Wk^T@T)
#define WS_CR    1315840u    // c_r[128] f32
#define WS_W6    1316352u    // W6[128][128] f32 (Wv@Wc1)
#define WS_U6    1381888u    // u6[128] f32 (Wv*bc1+bv)

__device__ __forceinline__ size_t wimg_off(int n, int k, int BN, int nK){
  int nt = n / BN, r = n % BN, kt = k >> 6;
  int slot = (((k & 63) >> 3) ^ (r & 7));
  return (size_t)(nt * nK + kt) * (size_t)(BN * 128) + (size_t)r * 128 + (slot << 4) + (k & 7) * 2;
}

// ---------------- prep1: T = Wq@Wc2 [128][256], u = Wq*bc2+bq ----------------
__global__ __launch_bounds__(256) void prep1_k(const float* __restrict__ wq, const float* __restrict__ bq,
                                               const float* __restrict__ wc2, const float* __restrict__ bc2,
                                               char* ws)
{
  float* T = (float*)(ws + WS_T);
  float* u = (float*)(ws + WS_U);
  const int a = blockIdx.x, j = threadIdx.x;
  float s = 0.f;
  for (int c = 0; c < 128; c++) s += wq[a * 128 + c] * wc2[c * 256 + j];
  T[a * 256 + j] = s;
  if (j == 0){
    float su = bq[a];
    for (int c = 0; c < 128; c++) su += wq[a * 128 + c] * bc2[c];
    u[a] = su;
  }
}

// ---------------- prep1b: M_r = 0.5*Wk^T@T, c_r ; W6 = Wv@Wc1, u6 ----------------
__global__ __launch_bounds__(256) void prep1b_k(const float* __restrict__ wk,
                                                const float* __restrict__ wv,
                                                const float* __restrict__ wc1,
                                                const float* __restrict__ bc1,
                                                const float* __restrict__ bv,
                                                char* ws)
{
  const float* T = (const float*)(ws + WS_T);
  const float* u = (const float*)(ws + WS_U);
  const int blk = blockIdx.x, j = threadIdx.x;
  if (blk < 128){
    int n = blk;
    float s = 0.f;
    for (int a = 0; a < 128; a++) s += wk[a * 128 + n] * T[a * 256 + j];
    ((float*)(ws + WS_MR))[n * 256 + j] = 0.5f * s;
    if (j == 0){
      float sc = 0.f;
      for (int a = 0; a < 128; a++) sc += wk[a * 128 + n] * u[a];
      ((float*)(ws + WS_CR))[n] = 0.5f * sc;
    }
  } else {
    int n = blk - 128;
    if (j < 128){
      float s = 0.f;
      for (int c = 0; c < 128; c++) s += wv[n * 128 + c] * wc1[c * 128 + j];
      ((float*)(ws + WS_W6))[n * 128 + j] = s;
    }
    if (j == 0){
      float s = bv[n];
      for (int c = 0; c < 128; c++) s += wv[n * 128 + c] * bc1[c];
      ((float*)(ws + WS_U6))[n] = s;
    }
  }
}

// ---------------- prep2: weight images + fused biases (A1 linear, validated r8) ----------------
__global__ __launch_bounds__(256) void prep2_k(
    const float* __restrict__ wc1, const float* __restrict__ wc2,
    const float* __restrict__ wdet, const float* __restrict__ bdet,
    const float* __restrict__ wm0, const float* __restrict__ bm0,
    const float* __restrict__ wm1, const float* __restrict__ bm1,
    char* ws)
{
  const float* MR = (const float*)(ws + WS_MR);
  const float* CR = (const float*)(ws + WS_CR);
  const float* W6 = (const float*)(ws + WS_W6);
  const float* U6 = (const float*)(ws + WS_U6);
  int idx = blockIdx.x * 256 + threadIdx.x;
  if (idx < 98304){                       // A1 linear [384][256]
    int n = idx >> 8, k = idx & 255;
    float s = 0.f;
    if (n < 128){
      for (int c = 0; c < 128; c++) s += wc1[c * 128 + n] * MR[c * 256 + k];
    } else if (n < 383){
      int oc = n - 128;
      for (int c = 0; c < 128; c++) s += wdet[oc * 128 + c] * wc2[c * 256 + k];
      s *= 0.5f;
    }
    ((u16*)(ws + WS_A1))[n * 256 + k] = f2bf(s);
  } else if (idx < 98688){                // c1[384] (s part; h0 const via prep2b)
    int n = idx - 98304;
    float s = 0.f;
    if (n < 128){
      for (int c = 0; c < 128; c++) s += wc1[c * 128 + n] * CR[c];
    }
    ((float*)(ws + WS_C1))[n] = s;
  } else if (idx < 131456){               // Wdvc [256][128] = 0.5*Wdet@W6
    int id = idx - 98688; int n = id >> 7, k = id & 127;
    float s = 0.f;
    if (n < 255){
      for (int c = 0; c < 128; c++) s += wdet[n * 128 + c] * W6[c * 128 + k];
      s *= 0.5f;
    }
    ((u16*)(ws + WS_WDVC))[n * 128 + k] = f2bf(s);
  } else if (idx < 131712){               // b3[256] = bdet + 0.5*Wdet@u6
    int n = idx - 131456;
    float s = 0.f;
    if (n < 255){
      float ss = 0.f;
      for (int c = 0; c < 128; c++) ss += wdet[n * 128 + c] * U6[c];
      s = bdet[n] + 0.5f * ss;
    }
    ((float*)(ws + WS_B3))[n] = s;
  } else if (idx < 262784){               // Wm0 image [256][512]
    int id = idx - 131712; int n = id >> 9, k = id & 511;
    float s = (n < 255) ? wm0[n * 512 + k] : 0.f;
    *(u16*)(ws + WS_WM0 + wimg_off(n, k, 256, 8)) = f2bf(s);
  } else if (idx < 524928){               // Wm1 image [256][1024]
    int id = idx - 262784; int n = id >> 10, k = id & 1023;
    float s = (n < 255) ? wm1[n * 1024 + k] : 0.f;
    *(u16*)(ws + WS_WM1 + wimg_off(n, k, 256, 16)) = f2bf(s);
  } else if (idx < 525440){               // bm0/bm1
    int id = idx - 524928;
    if (id < 256) ((float*)(ws + WS_BM0))[id] = (id < 255) ? bm0[id] : 0.f;
    else { int n = id - 256; ((float*)(ws + WS_BM1))[n] = (n < 255) ? bm1[n] : 0.f; }
  }
}

// ---------------- prep2b: c1[128+n] = 0.5*Wdet@bc2 ----------------
__global__ __launch_bounds__(256) void prep2b_k(const float* __restrict__ wdet,
                                                const float* __restrict__ bc2, char* ws)
{
  int n = threadIdx.x;
  float s = 0.f;
  if (n < 255){
    for (int c = 0; c < 128; c++) s += wdet[n * 128 + c] * bc2[c];
  }
  if (n < 256) ((float*)(ws + WS_C1))[128 + n] = 0.5f * s;
}

// ---------------- head MFMA GEMM (validated machinery, EPI=2 only) ----------------
template<int M, int Kd, int BM, int BN, int WM, int WN, int PPB, int Cin>
__global__ __launch_bounds__(256) void gemm_k(const float* __restrict__ Ap, const char* __restrict__ wimg,
                                              const float* __restrict__ bias, float* __restrict__ outp, long out_off)
{
  constexpr int nK  = Kd / 64;
  constexpr int TPP = 256 / BM;
  constexpr int CPT = 64 / TPP;
  __shared__ char lds[BM * 128 + BN * 128];
  char* ldsA = lds;
  char* ldsW = lds + BM * 128;
  const int t = threadIdx.x;
  const int lane = t & 63;
  const int wid = t >> 6;
  const int wm = wid / WN, wn = wid % WN;
  const int nt = blockIdx.x, mt = blockIdx.y;
  const int m0 = mt * BM, n0 = nt * BN;
  const int lr = lane & 15, lg = lane >> 4;
  f32x4 acc[4][4] = {};

  const int pi = t % BM, cb = t / BM;
  const float* asrc;
  {
    int mg = m0 + pi; int b = mg / PPB; int p = mg - b * PPB;
    asrc = Ap + (size_t)b * Cin * PPB + p;
  }

  for (int kt = 0; kt < nK; kt++){
    {
      float tf[CPT];
      const float* sp = asrc + (size_t)(kt * 64 + cb * CPT) * PPB;
      #pragma unroll
      for (int cc = 0; cc < CPT; cc++) tf[cc] = sp[(size_t)cc * PPB];
      #pragma unroll
      for (int g = 0; g < CPT / 8; g++){
        uint4 wv_;
        wv_.x = (u32)f2bf(tf[g*8+0]) | ((u32)f2bf(tf[g*8+1]) << 16);
        wv_.y = (u32)f2bf(tf[g*8+2]) | ((u32)f2bf(tf[g*8+3]) << 16);
        wv_.z = (u32)f2bf(tf[g*8+4]) | ((u32)f2bf(tf[g*8+5]) << 16);
        wv_.w = (u32)f2bf(tf[g*8+6]) | ((u32)f2bf(tf[g*8+7]) << 16);
        int chunk = cb * (CPT / 8) + g;
        *(uint4*)(ldsA + pi * 128 + ((chunk ^ (pi & 7)) << 4)) = wv_;
      }
    }
    {
      const char* srct = wimg + (size_t)(nt * nK + kt) * (BN * 128);
      #pragma unroll
      for (int it = 0; it < BN / 32; it++){
        int off = t * 16 + it * 4096;
        *(uint4*)(ldsW + off) = *(const uint4*)(srct + off);
      }
    }
    __syncthreads();
    #pragma unroll
    for (int ks = 0; ks < 2; ks++){
      bf16x8 af[4], bfr[4];
      #pragma unroll
      for (int i = 0; i < 4; i++){
        int r = wm * 64 + i * 16 + lr;
        af[i] = *(const bf16x8*)(ldsA + r * 128 + ((((ks << 2) + lg) ^ (r & 7)) << 4));
      }
      #pragma unroll
      for (int j = 0; j < 4; j++){
        int r = wn * 64 + j * 16 + lr;
        bfr[j] = *(const bf16x8*)(ldsW + r * 128 + ((((ks << 2) + lg) ^ (r & 7)) << 4));
      }
      #pragma unroll
      for (int i = 0; i < 4; i++)
        #pragma unroll
        for (int j = 0; j < 4; j++)
          acc[i][j] = __builtin_amdgcn_mfma_f32_16x16x32_bf16(af[i], bfr[j], acc[i][j], 0, 0, 0);
    }
    __syncthreads();
  }

  #pragma unroll
  for (int j = 0; j < 4; j++){
    int nn = n0 + wn * 64 + j * 16 + lr;
    float bs = bias[nn];
    #pragma unroll
    for (int i = 0; i < 4; i++){
      #pragma unroll
      for (int r = 0; r < 4; r++){
        int mm = m0 + wm * 64 + i * 16 + lg * 4 + r;
        float v = acc[i][j][r] + bs;
        if (nn < 255){
          int b = mm / PPB, p = mm - b * PPB;
          int a = nn / 85, o = nn - a * 85;
          outp[out_off + ((size_t)(b * 3 + a) * PPB + p) * 85 + o] = v;
        }
      }
    }
  }
}

// ---------------- clla: in-kernel s|h0 GEMM (LDS-staged x1) + dots/softmax/y/p0 ----------------
// LDS: x0s [64px][256B] swz @0 (16384, reused as fp32 p0 stage)
//      x1s [16px][512B] swz @16384 (8192)
//      rs  [16][256B] swz @24576 (4096; s then y)
//      h0s u16 [16][256] @28672 (8192)
__global__ __launch_bounds__(256) void clla_k(const float* __restrict__ x0,
                                              const float* __restrict__ x1,
                                              const char* __restrict__ ws,
                                              float* __restrict__ out)
{
  __shared__ char smem[36864];
  char* x0s = smem;
  char* x1s = smem + 16384;
  char* rs  = smem + 24576;
  u16*  h0s = (u16*)(smem + 28672);
  float* stg = (float*)smem;              // P5 stage over x0s

  const char*  a1l  = ws + WS_A1;
  const char*  wdvi = ws + WS_WDVC;
  const float* c1g  = (const float*)(ws + WS_C1);
  const float* b3   = (const float*)(ws + WS_B3);

  const int t = threadIdx.x;
  const int lane = t & 63, wid = t >> 6;
  const int lr = lane & 15, lg = lane >> 4;
  const int blk = blockIdx.x;
  const int b = blk / 400, rem = blk % 400;
  const int h = rem / 5, w0 = (rem % 5) * 16;
  const int pr = h * 80 + w0;

  // S1: stage x1 tile [16 px][256 ch] -> bf16 swizzled (coalesced, no redundancy)
  {
    const int px1 = t & 15, chg = t >> 4;          // 16 ch per thread
    const float* xq = x1 + (size_t)b * 256 * 6400 + (size_t)(chg * 16) * 6400 + pr + px1;
    float tx[16];
    #pragma unroll
    for (int i = 0; i < 16; i++) tx[i] = xq[(size_t)i * 6400];
    #pragma unroll
    for (int j = 0; j < 2; j++){
      uint4 wv_;
      wv_.x = (u32)f2bf(tx[j*8+0]) | ((u32)f2bf(tx[j*8+1]) << 16);
      wv_.y = (u32)f2bf(tx[j*8+2]) | ((u32)f2bf(tx[j*8+3]) << 16);
      wv_.z = (u32)f2bf(tx[j*8+4]) | ((u32)f2bf(tx[j*8+5]) << 16);
      wv_.w = (u32)f2bf(tx[j*8+6]) | ((u32)f2bf(tx[j*8+7]) << 16);
      int chunk = chg * 2 + j;
      *(uint4*)(x1s + px1 * 512 + (((chunk ^ ((px1 & 7) << 1)) & 31) << 4)) = wv_;
    }
  }
  __syncthreads();

  // S2: issue x0 loads (latency hides under P1b MFMA)
  const int f = t & 63, cq = t >> 6;
  float tf[32];
  {
    const int lc = f >> 2, n = f & 3;
    const float* gp = x0 + ((size_t)b * 128 + cq * 32) * 25600
                    + (size_t)(2 * h + (n >> 1)) * 160 + 2 * (w0 + lc) + (n & 1);
    #pragma unroll
    for (int cc = 0; cc < 32; cc++) tf[cc] = gp[(size_t)cc * 25600];
  }

  // P1b: s|h0 = A1 @ x1_tile + c1 via MFMA; wave wid owns n-tiles wid*6..wid*6+5
  {
    bf16x8 af[8];
    #pragma unroll
    for (int kk = 0; kk < 8; kk++){
      int chunk = kk * 4 + lg;
      af[kk] = *(const bf16x8*)(x1s + lr * 512 + (((chunk ^ ((lr & 7) << 1)) & 31) << 4));
    }
    #pragma unroll
    for (int jj = 0; jj < 6; jj++){
      int jn = wid * 6 + jj;
      f32x4 acc = (f32x4){0.f, 0.f, 0.f, 0.f};
      #pragma unroll
      for (int kk = 0; kk < 8; kk++){
        bf16x8 bfr = *(const bf16x8*)(a1l + (size_t)(jn * 16 + lr) * 512 + kk * 64 + lg * 16);
        acc = __builtin_amdgcn_mfma_f32_16x16x32_bf16(af[kk], bfr, acc, 0, 0, 0);
      }
      int col = jn * 16 + lr;
      float bs = c1g[col];
      #pragma unroll
      for (int ri = 0; ri < 4; ri++){
        int px = lg * 4 + ri;
        float v = acc[ri] + bs;
        if (col < 128){
          *(u16*)(rs + px * 256 + ((((col >> 3) ^ ((px & 7) << 1)) & 15) << 4) + (col & 7) * 2) = f2bf(v);
        } else if (col < 383){
          h0s[px * 256 + (col - 128)] = f2bf(v);
        }
      }
    }
  }

  // S3: commit x0 -> LDS (bf16 swizzled)
  {
    #pragma unroll
    for (int g = 0; g < 4; g++){
      uint4 wv_;
      wv_.x = (u32)f2bf(tf[g*8+0]) | ((u32)f2bf(tf[g*8+1]) << 16);
      wv_.y = (u32)f2bf(tf[g*8+2]) | ((u32)f2bf(tf[g*8+3]) << 16);
      wv_.z = (u32)f2bf(tf[g*8+4]) | ((u32)f2bf(tf[g*8+5]) << 16);
      wv_.w = (u32)f2bf(tf[g*8+6]) | ((u32)f2bf(tf[g*8+7]) << 16);
      int chunk = cq * 4 + g;
      *(uint4*)(x0s + f * 256 + (((chunk ^ ((f & 7) << 1)) & 15) << 4)) = wv_;
    }
  }
  __syncthreads();

  // P2: dots + softmax, all 256 threads: t = [px(4b)][n(2b)][cq(2b)]
  float myatt;
  {
    const int px = t >> 4, n = (t >> 2) & 3, cq2 = t & 3;
    const int fr = px * 4 + n;
    float d = 0.f;
    #pragma unroll
    for (int g = 0; g < 4; g++){
      int c = cq2 * 4 + g;
      bf16x8 rv = *(const bf16x8*)(rs  + px * 256 + (((c ^ ((px & 7) << 1)) & 15) << 4));
      bf16x8 fv = *(const bf16x8*)(x0s + fr * 256 + (((c ^ ((fr & 7) << 1)) & 15) << 4));
      #pragma unroll
      for (int e = 0; e < 8; e++) d += (float)rv[e] * (float)fv[e];
    }
    d += __shfl_xor(d, 1); d += __shfl_xor(d, 2);
    float s4 = d + __shfl_xor(d, 4); s4 += __shfl_xor(s4, 8);
    float irr = 0.5f * s4 - d;
    float mx = fmaxf(irr, __shfl_xor(irr, 4)); mx = fmaxf(mx, __shfl_xor(mx, 8));
    float e1 = __expf(irr - mx);
    float den = e1 + __shfl_xor(e1, 4); den += __shfl_xor(den, 8);
    myatt = e1 / den;                    // att[px][n] on every cq lane
  }
  // no barrier: rs row px / x0s quarter / att all wave-local for P3

  // P3: y = sum_n att*x0_n -> rs (overwrite s; same-wave rows) bf16 swizzled
  {
    const int px = t >> 4, cp = t & 15;
    float o[8];
    #pragma unroll
    for (int e = 0; e < 8; e++) o[e] = 0.f;
    #pragma unroll
    for (int n = 0; n < 4; n++){
      float a = __shfl(myatt, ((t & 48)) | (n << 2));   // lane (px&3)*16 + n*4 within wave
      int fr = px * 4 + n;
      bf16x8 fv = *(const bf16x8*)(x0s + fr * 256 + (((cp ^ ((fr & 7) << 1)) & 15) << 4));
      #pragma unroll
      for (int e = 0; e < 8; e++) o[e] += a * (float)fv[e];
    }
    uint4 wv_;
    wv_.x = (u32)f2bf(o[0]) | ((u32)f2bf(o[1]) << 16);
    wv_.y = (u32)f2bf(o[2]) | ((u32)f2bf(o[3]) << 16);
    wv_.z = (u32)f2bf(o[4]) | ((u32)f2bf(o[5]) << 16);
    wv_.w = (u32)f2bf(o[6]) | ((u32)f2bf(o[7]) << 16);
    *(uint4*)(rs + px * 256 + (((cp ^ ((px & 7) << 1)) & 15) << 4)) = wv_;
  }
  __syncthreads();

  // P4: p0 = Wdvc @ y + h0 + b3 via MFMA -> fp32 LDS stage (x0s region dead)
  {
    bf16x8 af[4];
    #pragma unroll
    for (int kt = 0; kt < 4; kt++){
      int chunk = kt * 4 + lg;
      af[kt] = *(const bf16x8*)(rs + lr * 256 + (((chunk ^ ((lr & 7) << 1)) & 15) << 4));
    }
    #pragma unroll
    for (int jj = 0; jj < 4; jj++){
      int jn = wid * 4 + jj;
      f32x4 acc = (f32x4){0.f, 0.f, 0.f, 0.f};
      #pragma unroll
      for (int kt = 0; kt < 4; kt++){
        bf16x8 bfr = *(const bf16x8*)(wdvi + (jn * 16 + lr) * 256 + (kt * 4 + lg) * 16);
        acc = __builtin_amdgcn_mfma_f32_16x16x32_bf16(af[kt], bfr, acc, 0, 0, 0);
      }
      int oc = jn * 16 + lr;
      if (oc < 255){
        int a = oc / 85, o = oc - a * 85;
        #pragma unroll
        for (int ri = 0; ri < 4; ri++){
          int px = lg * 4 + ri;
          float v = acc[ri] + bf2f(h0s[px * 256 + oc]) + b3[oc];
          stg[a * 1360 + px * 85 + o] = v;
        }
      }
    }
  }
  __syncthreads();

  // P5: coalesced p0 store (3 contiguous 5440B segments)
  {
    #pragma unroll
    for (int it = 0; it < 16; it++){
      int idx = it * 256 + t;
      if (idx < 4080){
        int a = idx / 1360, r = idx - a * 1360;
        out[((size_t)(b * 3 + a) * 6400 + pr) * 85 + r] = stg[idx];
      }
    }
  }
}

extern "C" void kernel_launch(void* const* d_in, const int* in_sizes, int n_in,
                              void* d_out, int out_size, void* d_ws, size_t ws_size,
                              hipStream_t stream)
{
  (void)in_sizes; (void)n_in; (void)out_size; (void)ws_size;
  const float* x0  = (const float*)d_in[0];
  const float* x1  = (const float*)d_in[1];
  const float* x2  = (const float*)d_in[2];
  const float* x3  = (const float*)d_in[3];
  const float* wc1 = (const float*)d_in[4];  const float* bc1 = (const float*)d_in[5];
  const float* wc2 = (const float*)d_in[6];  const float* bc2 = (const float*)d_in[7];
  const float* wq  = (const float*)d_in[8];  const float* bq  = (const float*)d_in[9];
  const float* wk  = (const float*)d_in[10];
  const float* wv  = (const float*)d_in[12]; const float* bv  = (const float*)d_in[13];
  const float* wdt = (const float*)d_in[14]; const float* bdt = (const float*)d_in[15];
  const float* wm0 = (const float*)d_in[16]; const float* bm0 = (const float*)d_in[17];
  const float* wm1 = (const float*)d_in[18]; const float* bm1 = (const float*)d_in[19];
  char* ws = (char*)d_ws;
  float* out = (float*)d_out;

  prep1_k<<<128, 256, 0, stream>>>(wq, bq, wc2, bc2, ws);
  prep1b_k<<<256, 256, 0, stream>>>(wk, wv, wc1, bc1, bv, ws);
  prep2_k<<<2053, 256, 0, stream>>>(wc1, wc2, wdt, bdt, wm0, bm0, wm1, bm1, ws);
  prep2b_k<<<1, 256, 0, stream>>>(wdt, bc2, ws);
  // fused: x1-GEMM (s|h0) + dots/softmax/y/p0
  clla_k<<<3200, 256, 0, stream>>>(x0, x1, ws, out);
  // p1 = head(x2 @ Wm0^T)
  gemm_k<12800, 512, 64, 256, 1, 4, 1600, 512>
      <<<dim3(1, 200), 256, 0, stream>>>(x2, ws + WS_WM0, (const float*)(ws + WS_BM0), out, 13056000L);
  // p2 = head(x3 @ Wm1^T)
  gemm_k<3200, 1024, 64, 256, 1, 4, 400, 1024>
      <<<dim3(1, 50), 256, 0, stream>>>(x3, ws + WS_WM1, (const float*)(ws + WS_BM1), out, 16320000L);
}

// Round 11
// 170.424 us; speedup vs baseline: 1.2472x; 1.2472x over previous
//
#include <hip/hip_runtime.h>

typedef unsigned short u16;
typedef unsigned int   u32;
typedef __bf16 bf16x8 __attribute__((ext_vector_type(8)));
typedef float  f32x4  __attribute__((ext_vector_type(4)));

__device__ __forceinline__ u16 f2bf(float f){
  u32 u = __float_as_uint(f);
  return (u16)((u + 0x7FFFu + ((u >> 16) & 1u)) >> 16);  // RNE
}
__device__ __forceinline__ float bf2f(u16 h){ return __uint_as_float(((u32)h) << 16); }

// ---------------- workspace layout (bytes) ----------------
#define WS_A1    0u          // A1 wimg [384][256] bf16 (BN=128,nK=4)   196608
#define WS_WM0   196608u     // Wm0 wimg [256][512]  (BN=256,nK=8)      262144
#define WS_WM1   458752u     // Wm1 wimg [256][1024] (BN=256,nK=16)     524288
#define WS_WDVC  983040u     // Wdvc = 0.5*Wdet@Wv@Wc1 linear [256][128] bf16  65536
#define WS_C1    1048576u    // c1[384] f32
#define WS_B3    1050112u    // b3[256] f32
#define WS_BM0   1051136u
#define WS_BM1   1052160u
#define WS_T     1053184u    // T[128][256] f32 (Wq@Wc2)
#define WS_U     1184256u    // u[128] f32
#define WS_MR    1184768u    // M_r[128][256] f32 (0.5*Wk^T@T)
#define WS_CR    1315840u    // c_r[128] f32
#define WS_W6    1316352u    // W6[128][128] f32 (Wv@Wc1)
#define WS_U6    1381888u    // u6[128] f32 (Wv*bc1+bv)
#define WS_R     1382400u    // R[51200][384] bf16 = [s(128)|h0(255)|pad]

__device__ __forceinline__ size_t wimg_off(int n, int k, int BN, int nK){
  int nt = n / BN, r = n % BN, kt = k >> 6;
  int slot = (((k & 63) >> 3) ^ (r & 7));
  return (size_t)(nt * nK + kt) * (size_t)(BN * 128) + (size_t)r * 128 + (slot << 4) + (k & 7) * 2;
}

// ---------------- prep1: T = Wq@Wc2 [128][256], u = Wq*bc2+bq ----------------
__global__ __launch_bounds__(256) void prep1_k(const float* __restrict__ wq, const float* __restrict__ bq,
                                               const float* __restrict__ wc2, const float* __restrict__ bc2,
                                               char* ws)
{
  float* T = (float*)(ws + WS_T);
  float* u = (float*)(ws + WS_U);
  const int a = blockIdx.x, j = threadIdx.x;
  float s = 0.f;
  for (int c = 0; c < 128; c++) s += wq[a * 128 + c] * wc2[c * 256 + j];
  T[a * 256 + j] = s;
  if (j == 0){
    float su = bq[a];
    for (int c = 0; c < 128; c++) su += wq[a * 128 + c] * bc2[c];
    u[a] = su;
  }
}

// ---------------- prep1b: M_r = 0.5*Wk^T@T, c_r ; W6 = Wv@Wc1, u6 ----------------
__global__ __launch_bounds__(256) void prep1b_k(const float* __restrict__ wk,
                                                const float* __restrict__ wv,
                                                const float* __restrict__ wc1,
                                                const float* __restrict__ bc1,
                                                const float* __restrict__ bv,
                                                char* ws)
{
  const float* T = (const float*)(ws + WS_T);
  const float* u = (const float*)(ws + WS_U);
  const int blk = blockIdx.x, j = threadIdx.x;
  if (blk < 128){
    int n = blk;
    float s = 0.f;
    for (int a = 0; a < 128; a++) s += wk[a * 128 + n] * T[a * 256 + j];
    ((float*)(ws + WS_MR))[n * 256 + j] = 0.5f * s;
    if (j == 0){
      float sc = 0.f;
      for (int a = 0; a < 128; a++) sc += wk[a * 128 + n] * u[a];
      ((float*)(ws + WS_CR))[n] = 0.5f * sc;
    }
  } else {
    int n = blk - 128;
    if (j < 128){
      float s = 0.f;
      for (int c = 0; c < 128; c++) s += wv[n * 128 + c] * wc1[c * 128 + j];
      ((float*)(ws + WS_W6))[n * 128 + j] = s;
    }
    if (j == 0){
      float s = bv[n];
      for (int c = 0; c < 128; c++) s += wv[n * 128 + c] * bc1[c];
      ((float*)(ws + WS_U6))[n] = s;
    }
  }
}

// ---------------- prep2: weight images + fused biases (incl. former prep2b) ----------------
__global__ __launch_bounds__(256) void prep2_k(
    const float* __restrict__ wc1, const float* __restrict__ wc2,
    const float* __restrict__ wdet, const float* __restrict__ bdet,
    const float* __restrict__ wm0, const float* __restrict__ bm0,
    const float* __restrict__ wm1, const float* __restrict__ bm1,
    const float* __restrict__ bc2, char* ws)
{
  const float* MR = (const float*)(ws + WS_MR);
  const float* CR = (const float*)(ws + WS_CR);
  const float* W6 = (const float*)(ws + WS_W6);
  const float* U6 = (const float*)(ws + WS_U6);
  int idx = blockIdx.x * 256 + threadIdx.x;
  if (idx < 98304){                       // A1 wimg [384][256]
    int n = idx >> 8, k = idx & 255;
    float s = 0.f;
    if (n < 128){
      for (int c = 0; c < 128; c++) s += wc1[c * 128 + n] * MR[c * 256 + k];
    } else if (n < 383){
      int oc = n - 128;
      for (int c = 0; c < 128; c++) s += wdet[oc * 128 + c] * wc2[c * 256 + k];
      s *= 0.5f;
    }
    *(u16*)(ws + WS_A1 + wimg_off(n, k, 128, 4)) = f2bf(s);
  } else if (idx < 98688){                // c1[384] (s part)
    int n = idx - 98304;
    float s = 0.f;
    if (n < 128){
      for (int c = 0; c < 128; c++) s += wc1[c * 128 + n] * CR[c];
    }
    ((float*)(ws + WS_C1))[n] = s;
  } else if (idx < 131456){               // Wdvc [256][128] = 0.5*Wdet@W6
    int id = idx - 98688; int n = id >> 7, k = id & 127;
    float s = 0.f;
    if (n < 255){
      for (int c = 0; c < 128; c++) s += wdet[n * 128 + c] * W6[c * 128 + k];
      s *= 0.5f;
    }
    ((u16*)(ws + WS_WDVC))[n * 128 + k] = f2bf(s);
  } else if (idx < 131712){               // b3[256] = bdet + 0.5*Wdet@u6
    int n = idx - 131456;
    float s = 0.f;
    if (n < 255){
      float ss = 0.f;
      for (int c = 0; c < 128; c++) ss += wdet[n * 128 + c] * U6[c];
      s = bdet[n] + 0.5f * ss;
    }
    ((float*)(ws + WS_B3))[n] = s;
  } else if (idx < 262784){               // Wm0 image [256][512]
    int id = idx - 131712; int n = id >> 9, k = id & 511;
    float s = (n < 255) ? wm0[n * 512 + k] : 0.f;
    *(u16*)(ws + WS_WM0 + wimg_off(n, k, 256, 8)) = f2bf(s);
  } else if (idx < 524928){               // Wm1 image [256][1024]
    int id = idx - 262784; int n = id >> 10, k = id & 1023;
    float s = (n < 255) ? wm1[n * 1024 + k] : 0.f;
    *(u16*)(ws + WS_WM1 + wimg_off(n, k, 256, 16)) = f2bf(s);
  } else if (idx < 525440){               // bm0/bm1
    int id = idx - 524928;
    if (id < 256) ((float*)(ws + WS_BM0))[id] = (id < 255) ? bm0[id] : 0.f;
    else { int n = id - 256; ((float*)(ws + WS_BM1))[n] = (n < 255) ? bm1[n] : 0.f; }
  } else if (idx < 525696){               // c1[128+n] = 0.5*Wdet@bc2 (former prep2b)
    int n = idx - 525440;
    float s = 0.f;
    if (n < 255){
      for (int c = 0; c < 128; c++) s += wdet[n * 128 + c] * bc2[c];
    }
    ((float*)(ws + WS_C1))[128 + n] = 0.5f * s;
  }
}

// ---------------- MFMA GEMM body (validated machinery as device function) ----------------
// EPI 0: bf16 rows of ROWB bytes ; EPI 2: fp32 det-head permute
template<int Kd, int BM, int BN, int WM, int WN, int PPB, int Cin, int EPI, int ROWB>
__device__ __forceinline__ void gemm_body(char* lds, int mt, int nt,
                                          const float* __restrict__ Ap, const char* __restrict__ wimg,
                                          const float* __restrict__ bias, void* __restrict__ outp, long out_off)
{
  constexpr int nK  = Kd / 64;
  constexpr int TPP = 256 / BM;
  constexpr int CPT = 64 / TPP;
  char* ldsA = lds;
  char* ldsW = lds + BM * 128;
  const int t = threadIdx.x;
  const int lane = t & 63;
  const int wid = t >> 6;
  const int wm = wid / WN, wn = wid % WN;
  const int m0 = mt * BM, n0 = nt * BN;
  const int lr = lane & 15, lg = lane >> 4;
  f32x4 acc[4][4] = {};

  const int pi = t % BM, cb = t / BM;
  const float* asrc;
  {
    int mg = m0 + pi; int b = mg / PPB; int p = mg - b * PPB;
    asrc = Ap + (size_t)b * Cin * PPB + p;
  }

  for (int kt = 0; kt < nK; kt++){
    {
      float tf[CPT];
      const float* sp = asrc + (size_t)(kt * 64 + cb * CPT) * PPB;
      #pragma unroll
      for (int cc = 0; cc < CPT; cc++) tf[cc] = sp[(size_t)cc * PPB];
      #pragma unroll
      for (int g = 0; g < CPT / 8; g++){
        uint4 wv_;
        wv_.x = (u32)f2bf(tf[g*8+0]) | ((u32)f2bf(tf[g*8+1]) << 16);
        wv_.y = (u32)f2bf(tf[g*8+2]) | ((u32)f2bf(tf[g*8+3]) << 16);
        wv_.z = (u32)f2bf(tf[g*8+4]) | ((u32)f2bf(tf[g*8+5]) << 16);
        wv_.w = (u32)f2bf(tf[g*8+6]) | ((u32)f2bf(tf[g*8+7]) << 16);
        int chunk = cb * (CPT / 8) + g;
        *(uint4*)(ldsA + pi * 128 + ((chunk ^ (pi & 7)) << 4)) = wv_;
      }
    }
    {
      const char* srct = wimg + (size_t)(nt * nK + kt) * (BN * 128);
      #pragma unroll
      for (int it = 0; it < BN / 32; it++){
        int off = t * 16 + it * 4096;
        *(uint4*)(ldsW + off) = *(const uint4*)(srct + off);
      }
    }
    __syncthreads();
    #pragma unroll
    for (int ks = 0; ks < 2; ks++){
      bf16x8 af[4], bfr[4];
      #pragma unroll
      for (int i = 0; i < 4; i++){
        int r = wm * 64 + i * 16 + lr;
        af[i] = *(const bf16x8*)(ldsA + r * 128 + ((((ks << 2) + lg) ^ (r & 7)) << 4));
      }
      #pragma unroll
      for (int j = 0; j < 4; j++){
        int r = wn * 64 + j * 16 + lr;
        bfr[j] = *(const bf16x8*)(ldsW + r * 128 + ((((ks << 2) + lg) ^ (r & 7)) << 4));
      }
      #pragma unroll
      for (int i = 0; i < 4; i++)
        #pragma unroll
        for (int j = 0; j < 4; j++)
          acc[i][j] = __builtin_amdgcn_mfma_f32_16x16x32_bf16(af[i], bfr[j], acc[i][j], 0, 0, 0);
    }
    __syncthreads();
  }

  #pragma unroll
  for (int j = 0; j < 4; j++){
    int nn = n0 + wn * 64 + j * 16 + lr;
    float bs = bias[nn];
    #pragma unroll
    for (int i = 0; i < 4; i++){
      #pragma unroll
      for (int r = 0; r < 4; r++){
        int mm = m0 + wm * 64 + i * 16 + lg * 4 + r;
        float v = acc[i][j][r] + bs;
        if constexpr (EPI == 0){
          *(u16*)((char*)outp + (size_t)mm * ROWB + nn * 2) = f2bf(v);
        } else {
          if (nn < 255){
            int b = mm / PPB, p = mm - b * PPB;
            int a = nn / 85, o = nn - a * 85;
            ((float*)outp)[out_off + ((size_t)(b * 3 + a) * PPB + p) * 85 + o] = v;
          }
        }
      }
    }
  }
}

// ---------------- combined GEMM dispatch: R (1200) | p1 (200) | p2 (50) ----------------
__global__ __launch_bounds__(256) void gemms_k(const float* __restrict__ x1,
                                               const float* __restrict__ x2,
                                               const float* __restrict__ x3,
                                               char* __restrict__ ws,
                                               float* __restrict__ out)
{
  __shared__ char lds[40960];
  const int bid = blockIdx.x;
  if (bid < 1200){
    gemm_body<256, 128, 128, 2, 2, 6400, 256, 0, 768>(lds, bid / 3, bid % 3,
        x1, ws + WS_A1, (const float*)(ws + WS_C1), ws + WS_R, 0L);
  } else if (bid < 1400){
    gemm_body<512, 64, 256, 1, 4, 1600, 512, 2, 0>(lds, bid - 1200, 0,
        x2, ws + WS_WM0, (const float*)(ws + WS_BM0), out, 13056000L);
  } else {
    gemm_body<1024, 64, 256, 1, 4, 400, 1024, 2, 0>(lds, bid - 1400, 0,
        x3, ws + WS_WM1, (const float*)(ws + WS_BM1), out, 16320000L);
  }
}

// ---------------- clla: r9 structure + shfl att broadcast (r10-validated) ----------------
// LDS: x0s [64px][256B] swz @0 (16384, reused as fp32 p0 stage)
//      rs [16][256B] @16384 (4096; s then y)
__global__ __launch_bounds__(256) void clla_k(const float* __restrict__ x0,
                                              const char* __restrict__ ws,
                                              float* __restrict__ out)
{
  __shared__ char smem[20480];
  char* x0s = smem;
  char* rs  = smem + 16384;
  float* stg = (float*)smem;              // P4/P5 stage over x0s

  const u16*  R    = (const u16*)(ws + WS_R);
  const char* Rb   = ws + WS_R;
  const char* wdvi = ws + WS_WDVC;
  const float* b3  = (const float*)(ws + WS_B3);

  const int t = threadIdx.x;
  const int lane = t & 63, wid = t >> 6;
  const int lr = lane & 15, lg = lane >> 4;
  const int blk = blockIdx.x;
  const int b = blk / 400, rem = blk % 400;
  const int h = rem / 5, w0 = (rem % 5) * 16;
  const int c0 = b * 6400 + h * 80 + w0;
  const int pr = h * 80 + w0;

  // P1: stage x0 (64 fine px x 128ch) -> bf16 swizzled ; stage s rows -> rs
  {
    const int f = t & 63, cq = t >> 6;
    const int lc = f >> 2, n = f & 3;
    const float* gp = x0 + ((size_t)b * 128 + cq * 32) * 25600
                    + (size_t)(2 * h + (n >> 1)) * 160 + 2 * (w0 + lc) + (n & 1);
    float tf[32];
    #pragma unroll
    for (int cc = 0; cc < 32; cc++) tf[cc] = gp[(size_t)cc * 25600];
    #pragma unroll
    for (int g = 0; g < 4; g++){
      uint4 wv_;
      wv_.x = (u32)f2bf(tf[g*8+0]) | ((u32)f2bf(tf[g*8+1]) << 16);
      wv_.y = (u32)f2bf(tf[g*8+2]) | ((u32)f2bf(tf[g*8+3]) << 16);
      wv_.z = (u32)f2bf(tf[g*8+4]) | ((u32)f2bf(tf[g*8+5]) << 16);
      wv_.w = (u32)f2bf(tf[g*8+6]) | ((u32)f2bf(tf[g*8+7]) << 16);
      int chunk = cq * 4 + g;
      *(uint4*)(x0s + f * 256 + (((chunk ^ ((f & 7) << 1)) & 15) << 4)) = wv_;
    }
    const int lc2 = t >> 4, c2 = t & 15;
    *(uint4*)(rs + lc2 * 256 + (((c2 ^ ((lc2 & 7) << 1)) & 15) << 4)) =
        *(const uint4*)(Rb + (size_t)(c0 + lc2) * 768 + c2 * 16);
  }
  __syncthreads();

  // P2: dots + softmax, all 256 threads: t = [px(4b)][n(2b)][cq(2b)]
  float myatt;
  {
    const int px = t >> 4, n = (t >> 2) & 3, cq2 = t & 3;
    const int fr = px * 4 + n;
    float d = 0.f;
    #pragma unroll
    for (int g = 0; g < 4; g++){
      int c = cq2 * 4 + g;
      bf16x8 rv = *(const bf16x8*)(rs  + px * 256 + (((c ^ ((px & 7) << 1)) & 15) << 4));
      bf16x8 fv = *(const bf16x8*)(x0s + fr * 256 + (((c ^ ((fr & 7) << 1)) & 15) << 4));
      #pragma unroll
      for (int e = 0; e < 8; e++) d += (float)rv[e] * (float)fv[e];
    }
    d += __shfl_xor(d, 1); d += __shfl_xor(d, 2);
    float s4 = d + __shfl_xor(d, 4); s4 += __shfl_xor(s4, 8);
    float irr = 0.5f * s4 - d;
    float mx = fmaxf(irr, __shfl_xor(irr, 4)); mx = fmaxf(mx, __shfl_xor(mx, 8));
    float e1 = __expf(irr - mx);
    float den = e1 + __shfl_xor(e1, 4); den += __shfl_xor(den, 8);
    myatt = e1 / den;                    // att[px][n] on every cq lane
  }
  // no barrier: rs row px / x0s quarters / att all wave-local for P3

  // P3: y = sum_n att*x0_n -> rs (overwrite s; same-wave rows) bf16 swizzled
  {
    const int px = t >> 4, cp = t & 15;
    float o[8];
    #pragma unroll
    for (int e = 0; e < 8; e++) o[e] = 0.f;
    #pragma unroll
    for (int n = 0; n < 4; n++){
      float a = __shfl(myatt, (t & 48) | (n << 2));
      int fr = px * 4 + n;
      bf16x8 fv = *(const bf16x8*)(x0s + fr * 256 + (((cp ^ ((fr & 7) << 1)) & 15) << 4));
      #pragma unroll
      for (int e = 0; e < 8; e++) o[e] += a * (float)fv[e];
    }
    uint4 wv_;
    wv_.x = (u32)f2bf(o[0]) | ((u32)f2bf(o[1]) << 16);
    wv_.y = (u32)f2bf(o[2]) | ((u32)f2bf(o[3]) << 16);
    wv_.z = (u32)f2bf(o[4]) | ((u32)f2bf(o[5]) << 16);
    wv_.w = (u32)f2bf(o[6]) | ((u32)f2bf(o[7]) << 16);
    *(uint4*)(rs + px * 256 + (((cp ^ ((px & 7) << 1)) & 15) << 4)) = wv_;
  }
  __syncthreads();

  // P4: p0 = Wdvc @ y + h0 + b3 via MFMA -> fp32 LDS stage (x0s region dead)
  {
    bf16x8 af[4];
    #pragma unroll
    for (int kt = 0; kt < 4; kt++){
      int chunk = kt * 4 + lg;
      af[kt] = *(const bf16x8*)(rs + lr * 256 + (((chunk ^ ((lr & 7) << 1)) & 15) << 4));
    }
    #pragma unroll
    for (int jj = 0; jj < 4; jj++){
      int jn = wid * 4 + jj;
      f32x4 acc = (f32x4){0.f, 0.f, 0.f, 0.f};
      #pragma unroll
      for (int kt = 0; kt < 4; kt++){
        bf16x8 bfr = *(const bf16x8*)(wdvi + (jn * 16 + lr) * 256 + (kt * 4 + lg) * 16);
        acc = __builtin_amdgcn_mfma_f32_16x16x32_bf16(af[kt], bfr, acc, 0, 0, 0);
      }
      int oc = jn * 16 + lr;
      if (oc < 255){
        int a = oc / 85, o = oc - a * 85;
        #pragma unroll
        for (int ri = 0; ri < 4; ri++){
          int px = lg * 4 + ri;
          float v = acc[ri] + bf2f(R[(size_t)(c0 + px) * 384 + 128 + oc]) + b3[oc];
          stg[a * 1360 + px * 85 + o] = v;
        }
      }
    }
  }
  __syncthreads();

  // P5: coalesced p0 store (3 contiguous 5440B segments)
  {
    #pragma unroll
    for (int it = 0; it < 16; it++){
      int idx = it * 256 + t;
      if (idx < 4080){
        int a = idx / 1360, r = idx - a * 1360;
        out[((size_t)(b * 3 + a) * 6400 + pr) * 85 + r] = stg[idx];
      }
    }
  }
}

extern "C" void kernel_launch(void* const* d_in, const int* in_sizes, int n_in,
                              void* d_out, int out_size, void* d_ws, size_t ws_size,
                              hipStream_t stream)
{
  (void)in_sizes; (void)n_in; (void)out_size; (void)ws_size;
  const float* x0  = (const float*)d_in[0];
  const float* x1  = (const float*)d_in[1];
  const float* x2  = (const float*)d_in[2];
  const float* x3  = (const float*)d_in[3];
  const float* wc1 = (const float*)d_in[4];  const float* bc1 = (const float*)d_in[5];
  const float* wc2 = (const float*)d_in[6];  const float* bc2 = (const float*)d_in[7];
  const float* wq  = (const float*)d_in[8];  const float* bq  = (const float*)d_in[9];
  const float* wk  = (const float*)d_in[10];
  const float* wv  = (const float*)d_in[12]; const float* bv  = (const float*)d_in[13];
  const float* wdt = (const float*)d_in[14]; const float* bdt = (const float*)d_in[15];
  const float* wm0 = (const float*)d_in[16]; const float* bm0 = (const float*)d_in[17];
  const float* wm1 = (const float*)d_in[18]; const float* bm1 = (const float*)d_in[19];
  char* ws = (char*)d_ws;
  float* out = (float*)d_out;

  prep1_k<<<128, 256, 0, stream>>>(wq, bq, wc2, bc2, ws);
  prep1b_k<<<256, 256, 0, stream>>>(wk, wv, wc1, bc1, bv, ws);
  prep2_k<<<2054, 256, 0, stream>>>(wc1, wc2, wdt, bdt, wm0, bm0, wm1, bm1, bc2, ws);
  // combined: R = A1@x1+c1 (blocks 0-1199) | p1 (1200-1399) | p2 (1400-1449)
  gemms_k<<<1450, 256, 0, stream>>>(x1, x2, x3, ws, out);
  // fused dots/softmax/y/p0
  clla_k<<<3200, 256, 0, stream>>>(x0, ws, out);
}

// Round 12
// 138.530 us; speedup vs baseline: 1.5343x; 1.2302x over previous
//
#include <hip/hip_runtime.h>

typedef unsigned short u16;
typedef unsigned int   u32;
typedef __bf16 bf16x8 __attribute__((ext_vector_type(8)));
typedef float  f32x4  __attribute__((ext_vector_type(4)));

__device__ __forceinline__ u16 f2bf(float f){
  u32 u = __float_as_uint(f);
  return (u16)((u + 0x7FFFu + ((u >> 16) & 1u)) >> 16);  // RNE
}
__device__ __forceinline__ float bf2f(u16 h){ return __uint_as_float(((u32)h) << 16); }

// ---------------- workspace layout (bytes) ----------------
#define WS_A1    0u          // A1 wimg [384][256] bf16 (BN=128,nK=4)   196608
#define WS_WM0   196608u     // Wm0 wimg [256][512]  (BN=256,nK=8)      262144
#define WS_WM1   458752u     // Wm1 wimg [256][1024] (BN=256,nK=16)     524288
#define WS_WDVC  983040u     // Wdvc = 0.5*Wdet@Wv@Wc1 linear [256][128] bf16  65536
#define WS_C1    1048576u    // c1[384] f32
#define WS_B3    1050112u    // b3[256] f32
#define WS_BM0   1051136u
#define WS_BM1   1052160u
#define WS_T     1053184u    // T[128][256] f32 (Wq@Wc2)
#define WS_U     1184256u    // u[128] f32
#define WS_MR    1184768u    // M_r[128][256] f32 (0.5*Wk^T@T)
#define WS_CR    1315840u    // c_r[128] f32
#define WS_W6    1316352u    // W6[128][128] f32 (Wv@Wc1)
#define WS_U6    1381888u    // u6[128] f32 (Wv*bc1+bv)
#define WS_R     1382400u    // R[51200][384] bf16 = [s(128)|h0(255)|pad]

__device__ __forceinline__ size_t wimg_off(int n, int k, int BN, int nK){
  int nt = n / BN, r = n % BN, kt = k >> 6;
  int slot = (((k & 63) >> 3) ^ (r & 7));
  return (size_t)(nt * nK + kt) * (size_t)(BN * 128) + (size_t)r * 128 + (slot << 4) + (k & 7) * 2;
}

// ---------------- prep1: T = Wq@Wc2 [128][256], u = Wq*bc2+bq ----------------
__global__ __launch_bounds__(256) void prep1_k(const float* __restrict__ wq, const float* __restrict__ bq,
                                               const float* __restrict__ wc2, const float* __restrict__ bc2,
                                               char* ws)
{
  float* T = (float*)(ws + WS_T);
  float* u = (float*)(ws + WS_U);
  const int a = blockIdx.x, j = threadIdx.x;
  float s = 0.f;
  for (int c = 0; c < 128; c++) s += wq[a * 128 + c] * wc2[c * 256 + j];
  T[a * 256 + j] = s;
  if (j == 0){
    float su = bq[a];
    for (int c = 0; c < 128; c++) su += wq[a * 128 + c] * bc2[c];
    u[a] = su;
  }
}

// ---------------- prep1b: M_r = 0.5*Wk^T@T, c_r ; W6 = Wv@Wc1, u6 ----------------
__global__ __launch_bounds__(256) void prep1b_k(const float* __restrict__ wk,
                                                const float* __restrict__ wv,
                                                const float* __restrict__ wc1,
                                                const float* __restrict__ bc1,
                                                const float* __restrict__ bv,
                                                char* ws)
{
  const float* T = (const float*)(ws + WS_T);
  const float* u = (const float*)(ws + WS_U);
  const int blk = blockIdx.x, j = threadIdx.x;
  if (blk < 128){
    int n = blk;
    float s = 0.f;
    for (int a = 0; a < 128; a++) s += wk[a * 128 + n] * T[a * 256 + j];
    ((float*)(ws + WS_MR))[n * 256 + j] = 0.5f * s;
    if (j == 0){
      float sc = 0.f;
      for (int a = 0; a < 128; a++) sc += wk[a * 128 + n] * u[a];
      ((float*)(ws + WS_CR))[n] = 0.5f * sc;
    }
  } else {
    int n = blk - 128;
    if (j < 128){
      float s = 0.f;
      for (int c = 0; c < 128; c++) s += wv[n * 128 + c] * wc1[c * 128 + j];
      ((float*)(ws + WS_W6))[n * 128 + j] = s;
    }
    if (j == 0){
      float s = bv[n];
      for (int c = 0; c < 128; c++) s += wv[n * 128 + c] * bc1[c];
      ((float*)(ws + WS_U6))[n] = s;
    }
  }
}

// ---------------- prep2: weight images + fused biases ----------------
__global__ __launch_bounds__(256) void prep2_k(
    const float* __restrict__ wc1, const float* __restrict__ wc2,
    const float* __restrict__ wdet, const float* __restrict__ bdet,
    const float* __restrict__ wm0, const float* __restrict__ bm0,
    const float* __restrict__ wm1, const float* __restrict__ bm1,
    const float* __restrict__ bc2, char* ws)
{
  const float* MR = (const float*)(ws + WS_MR);
  const float* CR = (const float*)(ws + WS_CR);
  const float* W6 = (const float*)(ws + WS_W6);
  const float* U6 = (const float*)(ws + WS_U6);
  int idx = blockIdx.x * 256 + threadIdx.x;
  if (idx < 98304){                       // A1 wimg [384][256]
    int n = idx >> 8, k = idx & 255;
    float s = 0.f;
    if (n < 128){
      for (int c = 0; c < 128; c++) s += wc1[c * 128 + n] * MR[c * 256 + k];
    } else if (n < 383){
      int oc = n - 128;
      for (int c = 0; c < 128; c++) s += wdet[oc * 128 + c] * wc2[c * 256 + k];
      s *= 0.5f;
    }
    *(u16*)(ws + WS_A1 + wimg_off(n, k, 128, 4)) = f2bf(s);
  } else if (idx < 98688){                // c1[384] (s part)
    int n = idx - 98304;
    float s = 0.f;
    if (n < 128){
      for (int c = 0; c < 128; c++) s += wc1[c * 128 + n] * CR[c];
    }
    ((float*)(ws + WS_C1))[n] = s;
  } else if (idx < 131456){               // Wdvc [256][128] = 0.5*Wdet@W6
    int id = idx - 98688; int n = id >> 7, k = id & 127;
    float s = 0.f;
    if (n < 255){
      for (int c = 0; c < 128; c++) s += wdet[n * 128 + c] * W6[c * 128 + k];
      s *= 0.5f;
    }
    ((u16*)(ws + WS_WDVC))[n * 128 + k] = f2bf(s);
  } else if (idx < 131712){               // b3[256] = bdet + 0.5*Wdet@u6
    int n = idx - 131456;
    float s = 0.f;
    if (n < 255){
      float ss = 0.f;
      for (int c = 0; c < 128; c++) ss += wdet[n * 128 + c] * U6[c];
      s = bdet[n] + 0.5f * ss;
    }
    ((float*)(ws + WS_B3))[n] = s;
  } else if (idx < 262784){               // Wm0 image [256][512]
    int id = idx - 131712; int n = id >> 9, k = id & 511;
    float s = (n < 255) ? wm0[n * 512 + k] : 0.f;
    *(u16*)(ws + WS_WM0 + wimg_off(n, k, 256, 8)) = f2bf(s);
  } else if (idx < 524928){               // Wm1 image [256][1024]
    int id = idx - 262784; int n = id >> 10, k = id & 1023;
    float s = (n < 255) ? wm1[n * 1024 + k] : 0.f;
    *(u16*)(ws + WS_WM1 + wimg_off(n, k, 256, 16)) = f2bf(s);
  } else if (idx < 525440){               // bm0/bm1
    int id = idx - 524928;
    if (id < 256) ((float*)(ws + WS_BM0))[id] = (id < 255) ? bm0[id] : 0.f;
    else { int n = id - 256; ((float*)(ws + WS_BM1))[n] = (n < 255) ? bm1[n] : 0.f; }
  } else if (idx < 525696){               // c1[128+n] = 0.5*Wdet@bc2
    int n = idx - 525440;
    float s = 0.f;
    if (n < 255){
      for (int c = 0; c < 128; c++) s += wdet[n * 128 + c] * bc2[c];
    }
    ((float*)(ws + WS_C1))[128 + n] = 0.5f * s;
  }
}

// ---------------- MFMA GEMM body: float4 A-staging + LDS-staged R epilogue ----------------
// EPI 0: bf16 rows of ROWB bytes (coalesced via LDS) ; EPI 2: fp32 det-head permute
template<int Kd, int BM, int BN, int WM, int WN, int PPB, int Cin, int EPI, int ROWB>
__device__ __forceinline__ void gemm_body(char* lds, int mt, int nt,
                                          const float* __restrict__ Ap, const char* __restrict__ wimg,
                                          const float* __restrict__ bias, void* __restrict__ outp, long out_off)
{
  constexpr int nK = Kd / 64;
  constexpr int NV = BM / 16;       // float4s per thread per k-tile
  char* ldsA = lds;
  char* ldsW = lds + BM * 128;
  const int t = threadIdx.x;
  const int lane = t & 63;
  const int wid = t >> 6;
  const int wm = wid / WN, wn = wid % WN;
  const int m0 = mt * BM, n0 = nt * BN;
  const int lr = lane & 15, lg = lane >> 4;
  f32x4 acc[4][4] = {};

  const int q = t & 3, chl = t >> 2;             // px quarter-group, channel 0..63
  const int chunkA = chl >> 3, elo = (chl & 7) * 2;

  for (int kt = 0; kt < nK; kt++){
    {
      const int c = kt * 64 + chl;
      float4 v4[NV];
      #pragma unroll
      for (int v = 0; v < NV; v++){
        int pg = m0 + v * 16 + q * 4;            // global pixel (float4-aligned)
        int bb = pg / PPB, pp = pg - bb * PPB;
        v4[v] = *(const float4*)(Ap + (size_t)bb * Cin * PPB + (size_t)c * PPB + pp);
      }
      #pragma unroll
      for (int v = 0; v < NV; v++){
        #pragma unroll
        for (int e = 0; e < 4; e++){
          int pi = v * 16 + q * 4 + e;
          float val = ((const float*)&v4[v])[e];
          *(u16*)(ldsA + pi * 128 + ((chunkA ^ (pi & 7)) << 4) + elo) = f2bf(val);
        }
      }
    }
    {
      const char* srct = wimg + (size_t)(nt * nK + kt) * (BN * 128);
      #pragma unroll
      for (int it = 0; it < BN / 32; it++){
        int off = t * 16 + it * 4096;
        *(uint4*)(ldsW + off) = *(const uint4*)(srct + off);
      }
    }
    __syncthreads();
    #pragma unroll
    for (int ks = 0; ks < 2; ks++){
      bf16x8 af[4], bfr[4];
      #pragma unroll
      for (int i = 0; i < 4; i++){
        int r = wm * 64 + i * 16 + lr;
        af[i] = *(const bf16x8*)(ldsA + r * 128 + ((((ks << 2) + lg) ^ (r & 7)) << 4));
      }
      #pragma unroll
      for (int j = 0; j < 4; j++){
        int r = wn * 64 + j * 16 + lr;
        bfr[j] = *(const bf16x8*)(ldsW + r * 128 + ((((ks << 2) + lg) ^ (r & 7)) << 4));
      }
      #pragma unroll
      for (int i = 0; i < 4; i++)
        #pragma unroll
        for (int j = 0; j < 4; j++)
          acc[i][j] = __builtin_amdgcn_mfma_f32_16x16x32_bf16(af[i], bfr[j], acc[i][j], 0, 0, 0);
    }
    __syncthreads();
  }

  if constexpr (EPI == 0){
    // stage C in LDS [BM][136] u16 (272B stride, 16B-aligned rows), coalesced store
    u16* lds2 = (u16*)lds;
    #pragma unroll
    for (int j = 0; j < 4; j++){
      int nl = wn * 64 + j * 16 + lr;
      float bs = bias[n0 + nl];
      #pragma unroll
      for (int i = 0; i < 4; i++){
        #pragma unroll
        for (int r = 0; r < 4; r++){
          int ml = wm * 64 + i * 16 + lg * 4 + r;
          lds2[ml * 136 + nl] = f2bf(acc[i][j][r] + bs);
        }
      }
    }
    __syncthreads();
    char* outb = (char*)outp;
    #pragma unroll
    for (int it = 0; it < BM / 16; it++){
      int idx = it * 256 + t;                    // BM*16 uint4 total
      int row = idx >> 4, c16 = idx & 15;
      *(uint4*)(outb + (size_t)(m0 + row) * ROWB + n0 * 2 + c16 * 16) =
          *(const uint4*)((const char*)lds2 + row * 272 + c16 * 16);
    }
  } else {
    #pragma unroll
    for (int j = 0; j < 4; j++){
      int nn = n0 + wn * 64 + j * 16 + lr;
      float bs = bias[nn];
      #pragma unroll
      for (int i = 0; i < 4; i++){
        #pragma unroll
        for (int r = 0; r < 4; r++){
          int mm = m0 + wm * 64 + i * 16 + lg * 4 + r;
          float v = acc[i][j][r] + bs;
          if (nn < 255){
            int b = mm / PPB, p = mm - b * PPB;
            int a = nn / 85, o = nn - a * 85;
            ((float*)outp)[out_off + ((size_t)(b * 3 + a) * PPB + p) * 85 + o] = v;
          }
        }
      }
    }
  }
}

// ---------------- combined GEMM dispatch: p2 (50) | p1 (200) | R (1200) — long blocks first ----
__global__ __launch_bounds__(256) void gemms_k(const float* __restrict__ x1,
                                               const float* __restrict__ x2,
                                               const float* __restrict__ x3,
                                               char* __restrict__ ws,
                                               float* __restrict__ out)
{
  __shared__ char lds[40960];
  const int bid = blockIdx.x;
  if (bid < 50){
    gemm_body<1024, 64, 256, 1, 4, 400, 1024, 2, 0>(lds, bid, 0,
        x3, ws + WS_WM1, (const float*)(ws + WS_BM1), out, 16320000L);
  } else if (bid < 250){
    gemm_body<512, 64, 256, 1, 4, 1600, 512, 2, 0>(lds, bid - 50, 0,
        x2, ws + WS_WM0, (const float*)(ws + WS_BM0), out, 13056000L);
  } else {
    int b2 = bid - 250;
    gemm_body<256, 128, 128, 2, 2, 6400, 256, 0, 768>(lds, b2 / 3, b2 % 3,
        x1, ws + WS_A1, (const float*)(ws + WS_C1), ws + WS_R, 0L);
  }
}

// ---------------- clla: float4 x0 staging + dots/softmax/y/p0 ----------------
// LDS: x0s [64px][256B] swz @0 (16384, reused as fp32 p0 stage)
//      rs [16][256B] @16384 (4096; s then y)
__global__ __launch_bounds__(256) void clla_k(const float* __restrict__ x0,
                                              const char* __restrict__ ws,
                                              float* __restrict__ out)
{
  __shared__ char smem[20480];
  char* x0s = smem;
  char* rs  = smem + 16384;
  float* stg = (float*)smem;              // P4/P5 stage over x0s

  const u16*  R    = (const u16*)(ws + WS_R);
  const char* Rb   = ws + WS_R;
  const char* wdvi = ws + WS_WDVC;
  const float* b3  = (const float*)(ws + WS_B3);

  const int t = threadIdx.x;
  const int lane = t & 63, wid = t >> 6;
  const int lr = lane & 15, lg = lane >> 4;
  const int blk = blockIdx.x;
  const int b = blk / 400, rem = blk % 400;
  const int h = rem / 5, w0 = (rem % 5) * 16;
  const int c0 = b * 6400 + h * 80 + w0;
  const int pr = h * 80 + w0;

  // P1: float4 x0 staging: thread = (channel, fine-row); 8x float4 along cols
  {
    const int ch = t >> 1, r = t & 1;
    const float* gp = x0 + ((size_t)b * 128 + ch) * 25600
                    + (size_t)(2 * h + r) * 160 + 2 * w0;
    float4 v4[8];
    #pragma unroll
    for (int i = 0; i < 8; i++) v4[i] = *(const float4*)(gp + i * 4);
    const int chunk = ch >> 3, elo = (ch & 7) * 2;
    #pragma unroll
    for (int i = 0; i < 8; i++){
      #pragma unroll
      for (int e = 0; e < 4; e++){
        int j = i * 4 + e;                       // col 0..31
        int fr = ((j >> 1) << 2) + r * 2 + (j & 1);
        float val = ((const float*)&v4[i])[e];
        *(u16*)(x0s + fr * 256 + (((chunk ^ ((fr & 7) << 1)) & 15) << 4) + elo) = f2bf(val);
      }
    }
    const int lc2 = t >> 4, c2 = t & 15;
    *(uint4*)(rs + lc2 * 256 + (((c2 ^ ((lc2 & 7) << 1)) & 15) << 4)) =
        *(const uint4*)(Rb + (size_t)(c0 + lc2) * 768 + c2 * 16);
  }
  __syncthreads();

  // P2: dots + softmax, all 256 threads: t = [px(4b)][n(2b)][cq(2b)]
  float myatt;
  {
    const int px = t >> 4, n = (t >> 2) & 3, cq2 = t & 3;
    const int fr = px * 4 + n;
    float d = 0.f;
    #pragma unroll
    for (int g = 0; g < 4; g++){
      int c = cq2 * 4 + g;
      bf16x8 rv = *(const bf16x8*)(rs  + px * 256 + (((c ^ ((px & 7) << 1)) & 15) << 4));
      bf16x8 fv = *(const bf16x8*)(x0s + fr * 256 + (((c ^ ((fr & 7) << 1)) & 15) << 4));
      #pragma unroll
      for (int e = 0; e < 8; e++) d += (float)rv[e] * (float)fv[e];
    }
    d += __shfl_xor(d, 1); d += __shfl_xor(d, 2);
    float s4 = d + __shfl_xor(d, 4); s4 += __shfl_xor(s4, 8);
    float irr = 0.5f * s4 - d;
    float mx = fmaxf(irr, __shfl_xor(irr, 4)); mx = fmaxf(mx, __shfl_xor(mx, 8));
    float e1 = __expf(irr - mx);
    float den = e1 + __shfl_xor(e1, 4); den += __shfl_xor(den, 8);
    myatt = e1 / den;
  }
  // no barrier: rs row px / x0s quarters / att all wave-local for P3

  // P3: y = sum_n att*x0_n -> rs bf16 swizzled
  {
    const int px = t >> 4, cp = t & 15;
    float o[8];
    #pragma unroll
    for (int e = 0; e < 8; e++) o[e] = 0.f;
    #pragma unroll
    for (int n = 0; n < 4; n++){
      float a = __shfl(myatt, (t & 48) | (n << 2));
      int fr = px * 4 + n;
      bf16x8 fv = *(const bf16x8*)(x0s + fr * 256 + (((cp ^ ((fr & 7) << 1)) & 15) << 4));
      #pragma unroll
      for (int e = 0; e < 8; e++) o[e] += a * (float)fv[e];
    }
    uint4 wv_;
    wv_.x = (u32)f2bf(o[0]) | ((u32)f2bf(o[1]) << 16);
    wv_.y = (u32)f2bf(o[2]) | ((u32)f2bf(o[3]) << 16);
    wv_.z = (u32)f2bf(o[4]) | ((u32)f2bf(o[5]) << 16);
    wv_.w = (u32)f2bf(o[6]) | ((u32)f2bf(o[7]) << 16);
    *(uint4*)(rs + px * 256 + (((cp ^ ((px & 7) << 1)) & 15) << 4)) = wv_;
  }
  __syncthreads();

  // P4: p0 = Wdvc @ y + h0 + b3 via MFMA -> fp32 LDS stage
  {
    bf16x8 af[4];
    #pragma unroll
    for (int kt = 0; kt < 4; kt++){
      int chunk = kt * 4 + lg;
      af[kt] = *(const bf16x8*)(rs + lr * 256 + (((chunk ^ ((lr & 7) << 1)) & 15) << 4));
    }
    #pragma unroll
    for (int jj = 0; jj < 4; jj++){
      int jn = wid * 4 + jj;
      f32x4 acc = (f32x4){0.f, 0.f, 0.f, 0.f};
      #pragma unroll
      for (int kt = 0; kt < 4; kt++){
        bf16x8 bfr = *(const bf16x8*)(wdvi + (jn * 16 + lr) * 256 + (kt * 4 + lg) * 16);
        acc = __builtin_amdgcn_mfma_f32_16x16x32_bf16(af[kt], bfr, acc, 0, 0, 0);
      }
      int oc = jn * 16 + lr;
      if (oc < 255){
        int a = oc / 85, o = oc - a * 85;
        #pragma unroll
        for (int ri = 0; ri < 4; ri++){
          int px = lg * 4 + ri;
          float v = acc[ri] + bf2f(R[(size_t)(c0 + px) * 384 + 128 + oc]) + b3[oc];
          stg[a * 1360 + px * 85 + o] = v;
        }
      }
    }
  }
  __syncthreads();

  // P5: coalesced p0 store (3 contiguous 5440B segments)
  {
    #pragma unroll
    for (int it = 0; it < 16; it++){
      int idx = it * 256 + t;
      if (idx < 4080){
        int a = idx / 1360, r = idx - a * 1360;
        out[((size_t)(b * 3 + a) * 6400 + pr) * 85 + r] = stg[idx];
      }
    }
  }
}

extern "C" void kernel_launch(void* const* d_in, const int* in_sizes, int n_in,
                              void* d_out, int out_size, void* d_ws, size_t ws_size,
                              hipStream_t stream)
{
  (void)in_sizes; (void)n_in; (void)out_size; (void)ws_size;
  const float* x0  = (const float*)d_in[0];
  const float* x1  = (const float*)d_in[1];
  const float* x2  = (const float*)d_in[2];
  const float* x3  = (const float*)d_in[3];
  const float* wc1 = (const float*)d_in[4];  const float* bc1 = (const float*)d_in[5];
  const float* wc2 = (const float*)d_in[6];  const float* bc2 = (const float*)d_in[7];
  const float* wq  = (const float*)d_in[8];  const float* bq  = (const float*)d_in[9];
  const float* wk  = (const float*)d_in[10];
  const float* wv  = (const float*)d_in[12]; const float* bv  = (const float*)d_in[13];
  const float* wdt = (const float*)d_in[14]; const float* bdt = (const float*)d_in[15];
  const float* wm0 = (const float*)d_in[16]; const float* bm0 = (const float*)d_in[17];
  const float* wm1 = (const float*)d_in[18]; const float* bm1 = (const float*)d_in[19];
  char* ws = (char*)d_ws;
  float* out = (float*)d_out;

  prep1_k<<<128, 256, 0, stream>>>(wq, bq, wc2, bc2, ws);
  prep1b_k<<<256, 256, 0, stream>>>(wk, wv, wc1, bc1, bv, ws);
  prep2_k<<<2054, 256, 0, stream>>>(wc1, wc2, wdt, bdt, wm0, bm0, wm1, bm1, bc2, ws);
  // combined: p2 (0-49) | p1 (50-249) | R = A1@x1+c1 (250-1449)
  gemms_k<<<1450, 256, 0, stream>>>(x1, x2, x3, ws, out);
  // fused dots/softmax/y/p0
  clla_k<<<3200, 256, 0, stream>>>(x0, ws, out);
}

// Round 13
// 123.917 us; speedup vs baseline: 1.7153x; 1.1179x over previous
//
#include <hip/hip_runtime.h>

typedef unsigned short u16;
typedef unsigned int   u32;
typedef __bf16 bf16x8 __attribute__((ext_vector_type(8)));
typedef float  f32x4  __attribute__((ext_vector_type(4)));

__device__ __forceinline__ u16 f2bf(float f){
  u32 u = __float_as_uint(f);
  return (u16)((u + 0x7FFFu + ((u >> 16) & 1u)) >> 16);  // RNE
}
__device__ __forceinline__ float bf2f(u16 h){ return __uint_as_float(((u32)h) << 16); }

// ---------------- workspace layout (bytes) ----------------
#define WS_A1    0u          // A1 wimg [384][256] bf16 (BN=128,nK=4)   196608
#define WS_WM0   196608u     // Wm0 wimg [256][512]  (BN=256,nK=8)      262144
#define WS_WM1   458752u     // Wm1 wimg [256][1024] (BN=256,nK=16)     524288
#define WS_WDVC  983040u     // Wdvc = 0.5*Wdet@Wv@Wc1 linear [256][128] bf16  65536
#define WS_C1    1048576u    // c1[384] f32 (h0 part includes b3 fold)
#define WS_BM0   1051136u
#define WS_BM1   1052160u
#define WS_T     1053184u    // T[128][256] f32 (Wq@Wc2)
#define WS_U     1184256u    // u[128] f32
#define WS_P     1184768u    // P[128][128] f32 (Wk@Wc1)
#define WS_W6    1316352u    // W6[128][128] f32 (Wv@Wc1)
#define WS_U6    1381888u    // u6[128] f32 (Wv*bc1+bv)
#define WS_R     1382400u    // R[51200][384] bf16 = [s(128)|h0(255)|pad]

__device__ __forceinline__ size_t wimg_off(int n, int k, int BN, int nK){
  int nt = n / BN, r = n % BN, kt = k >> 6;
  int slot = (((k & 63) >> 3) ^ (r & 7));
  return (size_t)(nt * nK + kt) * (size_t)(BN * 128) + (size_t)r * 128 + (slot << 4) + (k & 7) * 2;
}

// ---------------- prepA: T=Wq@Wc2, u ; P=Wk@Wc1 ; W6=Wv@Wc1, u6 (all independent) ----------------
__global__ __launch_bounds__(256) void prepA_k(const float* __restrict__ wq, const float* __restrict__ bq,
                                               const float* __restrict__ wc2, const float* __restrict__ bc2,
                                               const float* __restrict__ wk,  const float* __restrict__ wv,
                                               const float* __restrict__ wc1, const float* __restrict__ bc1,
                                               const float* __restrict__ bv,  char* ws)
{
  const int blk = blockIdx.x, j = threadIdx.x;
  if (blk < 128){
    int a = blk;
    float s = 0.f;
    for (int c = 0; c < 128; c++) s += wq[a * 128 + c] * wc2[c * 256 + j];
    ((float*)(ws + WS_T))[a * 256 + j] = s;
    if (j == 0){
      float su = bq[a];
      for (int c = 0; c < 128; c++) su += wq[a * 128 + c] * bc2[c];
      ((float*)(ws + WS_U))[a] = su;
    }
  } else if (blk < 256){
    int n = blk - 128;
    if (j < 128){
      float s = 0.f;
      for (int c = 0; c < 128; c++) s += wk[n * 128 + c] * wc1[c * 128 + j];
      ((float*)(ws + WS_P))[n * 128 + j] = s;
    }
  } else {
    int n = blk - 256;
    if (j < 128){
      float s = 0.f;
      for (int c = 0; c < 128; c++) s += wv[n * 128 + c] * wc1[c * 128 + j];
      ((float*)(ws + WS_W6))[n * 128 + j] = s;
    }
    if (j == 0){
      float s = bv[n];
      for (int c = 0; c < 128; c++) s += wv[n * 128 + c] * bc1[c];
      ((float*)(ws + WS_U6))[n] = s;
    }
  }
}

// ---------------- prep2: weight images + fused biases (A1 via P^T@T; b3 folded into c1) ----------------
__global__ __launch_bounds__(256) void prep2_k(
    const float* __restrict__ wc2,
    const float* __restrict__ wdet, const float* __restrict__ bdet,
    const float* __restrict__ wm0, const float* __restrict__ bm0,
    const float* __restrict__ wm1, const float* __restrict__ bm1,
    const float* __restrict__ bc2, char* ws)
{
  const float* T  = (const float*)(ws + WS_T);
  const float* u  = (const float*)(ws + WS_U);
  const float* P  = (const float*)(ws + WS_P);
  const float* W6 = (const float*)(ws + WS_W6);
  const float* U6 = (const float*)(ws + WS_U6);
  int idx = blockIdx.x * 256 + threadIdx.x;
  if (idx < 98304){                       // A1 wimg [384][256]
    int n = idx >> 8, k = idx & 255;
    float s = 0.f;
    if (n < 128){
      for (int i = 0; i < 128; i++) s += P[i * 128 + n] * T[i * 256 + k];
      s *= 0.5f;
    } else if (n < 383){
      int oc = n - 128;
      for (int c = 0; c < 128; c++) s += wdet[oc * 128 + c] * wc2[c * 256 + k];
      s *= 0.5f;
    }
    *(u16*)(ws + WS_A1 + wimg_off(n, k, 128, 4)) = f2bf(s);
  } else if (idx < 98688){                // c1[384]: s part + (h0 const + b3) fold
    int n = idx - 98304;
    float s = 0.f;
    if (n < 128){
      for (int i = 0; i < 128; i++) s += P[i * 128 + n] * u[i];
      s *= 0.5f;
    } else if (n < 383){
      int oc = n - 128;
      float ss = 0.f;
      for (int c = 0; c < 128; c++) ss += wdet[oc * 128 + c] * (bc2[c] + U6[c]);
      s = bdet[oc] + 0.5f * ss;
    }
    ((float*)(ws + WS_C1))[n] = s;
  } else if (idx < 131456){               // Wdvc [256][128] = 0.5*Wdet@W6
    int id = idx - 98688; int n = id >> 7, k = id & 127;
    float s = 0.f;
    if (n < 255){
      for (int c = 0; c < 128; c++) s += wdet[n * 128 + c] * W6[c * 128 + k];
      s *= 0.5f;
    }
    ((u16*)(ws + WS_WDVC))[n * 128 + k] = f2bf(s);
  } else if (idx < 262528){               // Wm0 image [256][512]
    int id = idx - 131456; int n = id >> 9, k = id & 511;
    float s = (n < 255) ? wm0[n * 512 + k] : 0.f;
    *(u16*)(ws + WS_WM0 + wimg_off(n, k, 256, 8)) = f2bf(s);
  } else if (idx < 524672){               // Wm1 image [256][1024]
    int id = idx - 262528; int n = id >> 10, k = id & 1023;
    float s = (n < 255) ? wm1[n * 1024 + k] : 0.f;
    *(u16*)(ws + WS_WM1 + wimg_off(n, k, 256, 16)) = f2bf(s);
  } else if (idx < 525184){               // bm0/bm1
    int id = idx - 524672;
    if (id < 256) ((float*)(ws + WS_BM0))[id] = (id < 255) ? bm0[id] : 0.f;
    else { int n = id - 256; ((float*)(ws + WS_BM1))[n] = (n < 255) ? bm1[n] : 0.f; }
  }
}

// ---------------- MFMA GEMM body (r12-validated): float4 A-staging + LDS-staged R epilogue ----------------
template<int Kd, int BM, int BN, int WM, int WN, int PPB, int Cin, int EPI, int ROWB>
__device__ __forceinline__ void gemm_body(char* lds, int mt, int nt,
                                          const float* __restrict__ Ap, const char* __restrict__ wimg,
                                          const float* __restrict__ bias, void* __restrict__ outp, long out_off)
{
  constexpr int nK = Kd / 64;
  constexpr int NV = BM / 16;
  char* ldsA = lds;
  char* ldsW = lds + BM * 128;
  const int t = threadIdx.x;
  const int lane = t & 63;
  const int wid = t >> 6;
  const int wm = wid / WN, wn = wid % WN;
  const int m0 = mt * BM, n0 = nt * BN;
  const int lr = lane & 15, lg = lane >> 4;
  f32x4 acc[4][4] = {};

  const int q = t & 3, chl = t >> 2;
  const int chunkA = chl >> 3, elo = (chl & 7) * 2;

  for (int kt = 0; kt < nK; kt++){
    {
      const int c = kt * 64 + chl;
      float4 v4[NV];
      #pragma unroll
      for (int v = 0; v < NV; v++){
        int pg = m0 + v * 16 + q * 4;
        int bb = pg / PPB, pp = pg - bb * PPB;
        v4[v] = *(const float4*)(Ap + (size_t)bb * Cin * PPB + (size_t)c * PPB + pp);
      }
      #pragma unroll
      for (int v = 0; v < NV; v++){
        #pragma unroll
        for (int e = 0; e < 4; e++){
          int pi = v * 16 + q * 4 + e;
          float val = ((const float*)&v4[v])[e];
          *(u16*)(ldsA + pi * 128 + ((chunkA ^ (pi & 7)) << 4) + elo) = f2bf(val);
        }
      }
    }
    {
      const char* srct = wimg + (size_t)(nt * nK + kt) * (BN * 128);
      #pragma unroll
      for (int it = 0; it < BN / 32; it++){
        int off = t * 16 + it * 4096;
        *(uint4*)(ldsW + off) = *(const uint4*)(srct + off);
      }
    }
    __syncthreads();
    #pragma unroll
    for (int ks = 0; ks < 2; ks++){
      bf16x8 af[4], bfr[4];
      #pragma unroll
      for (int i = 0; i < 4; i++){
        int r = wm * 64 + i * 16 + lr;
        af[i] = *(const bf16x8*)(ldsA + r * 128 + ((((ks << 2) + lg) ^ (r & 7)) << 4));
      }
      #pragma unroll
      for (int j = 0; j < 4; j++){
        int r = wn * 64 + j * 16 + lr;
        bfr[j] = *(const bf16x8*)(ldsW + r * 128 + ((((ks << 2) + lg) ^ (r & 7)) << 4));
      }
      #pragma unroll
      for (int i = 0; i < 4; i++)
        #pragma unroll
        for (int j = 0; j < 4; j++)
          acc[i][j] = __builtin_amdgcn_mfma_f32_16x16x32_bf16(af[i], bfr[j], acc[i][j], 0, 0, 0);
    }
    __syncthreads();
  }

  if constexpr (EPI == 0){
    u16* lds2 = (u16*)lds;
    #pragma unroll
    for (int j = 0; j < 4; j++){
      int nl = wn * 64 + j * 16 + lr;
      float bs = bias[n0 + nl];
      #pragma unroll
      for (int i = 0; i < 4; i++){
        #pragma unroll
        for (int r = 0; r < 4; r++){
          int ml = wm * 64 + i * 16 + lg * 4 + r;
          lds2[ml * 136 + nl] = f2bf(acc[i][j][r] + bs);
        }
      }
    }
    __syncthreads();
    char* outb = (char*)outp;
    #pragma unroll
    for (int it = 0; it < BM / 16; it++){
      int idx = it * 256 + t;
      int row = idx >> 4, c16 = idx & 15;
      *(uint4*)(outb + (size_t)(m0 + row) * ROWB + n0 * 2 + c16 * 16) =
          *(const uint4*)((const char*)lds2 + row * 272 + c16 * 16);
    }
  } else {
    #pragma unroll
    for (int j = 0; j < 4; j++){
      int nn = n0 + wn * 64 + j * 16 + lr;
      float bs = bias[nn];
      #pragma unroll
      for (int i = 0; i < 4; i++){
        #pragma unroll
        for (int r = 0; r < 4; r++){
          int mm = m0 + wm * 64 + i * 16 + lg * 4 + r;
          float v = acc[i][j][r] + bs;
          if (nn < 255){
            int b = mm / PPB, p = mm - b * PPB;
            int a = nn / 85, o = nn - a * 85;
            ((float*)outp)[out_off + ((size_t)(b * 3 + a) * PPB + p) * 85 + o] = v;
          }
        }
      }
    }
  }
}

// ---------------- combined GEMM dispatch: p2 (50) | p1 (200) | R (1200) ----------------
__global__ __launch_bounds__(256) void gemms_k(const float* __restrict__ x1,
                                               const float* __restrict__ x2,
                                               const float* __restrict__ x3,
                                               char* __restrict__ ws,
                                               float* __restrict__ out)
{
  __shared__ char lds[40960];
  const int bid = blockIdx.x;
  if (bid < 50){
    gemm_body<1024, 64, 256, 1, 4, 400, 1024, 2, 0>(lds, bid, 0,
        x3, ws + WS_WM1, (const float*)(ws + WS_BM1), out, 16320000L);
  } else if (bid < 250){
    gemm_body<512, 64, 256, 1, 4, 1600, 512, 2, 0>(lds, bid - 50, 0,
        x2, ws + WS_WM0, (const float*)(ws + WS_BM0), out, 13056000L);
  } else {
    int b2 = bid - 250;
    gemm_body<256, 128, 128, 2, 2, 6400, 256, 0, 768>(lds, b2 / 3, b2 % 3,
        x1, ws + WS_A1, (const float*)(ws + WS_C1), ws + WS_R, 0L);
  }
}

// ---------------- clla: h0 LDS-staged, b3 folded, float4 p0 store ----------------
// LDS: x0s [64px][256B] swz @0 (16384, reused as fp32 p0 stage)
//      rs  [16][256B] swz @16384 (4096; s then y)
//      h0s [16][544B] @20480 (8704)
__global__ __launch_bounds__(256) void clla_k(const float* __restrict__ x0,
                                              const char* __restrict__ ws,
                                              float* __restrict__ out)
{
  __shared__ char smem[29184];
  char* x0s = smem;
  char* rs  = smem + 16384;
  char* h0s = smem + 20480;
  float* stg = (float*)smem;              // P4/P5 stage over x0s

  const char* Rb   = ws + WS_R;
  const char* wdvi = ws + WS_WDVC;

  const int t = threadIdx.x;
  const int lane = t & 63, wid = t >> 6;
  const int lr = lane & 15, lg = lane >> 4;
  const int blk = blockIdx.x;
  const int b = blk / 400, rem = blk % 400;
  const int h = rem / 5, w0 = (rem % 5) * 16;
  const int c0 = b * 6400 + h * 80 + w0;
  const int pr = h * 80 + w0;

  // P1: float4 x0 staging ; stage s rows -> rs ; stage h0 rows -> h0s (coalesced)
  {
    const int ch = t >> 1, r = t & 1;
    const float* gp = x0 + ((size_t)b * 128 + ch) * 25600
                    + (size_t)(2 * h + r) * 160 + 2 * w0;
    float4 v4[8];
    #pragma unroll
    for (int i = 0; i < 8; i++) v4[i] = *(const float4*)(gp + i * 4);
    const int chunk = ch >> 3, elo = (ch & 7) * 2;
    #pragma unroll
    for (int i = 0; i < 8; i++){
      #pragma unroll
      for (int e = 0; e < 4; e++){
        int j = i * 4 + e;
        int fr = ((j >> 1) << 2) + r * 2 + (j & 1);
        float val = ((const float*)&v4[i])[e];
        *(u16*)(x0s + fr * 256 + (((chunk ^ ((fr & 7) << 1)) & 15) << 4) + elo) = f2bf(val);
      }
    }
    const int lc2 = t >> 4, c2 = t & 15;
    *(uint4*)(rs + lc2 * 256 + (((c2 ^ ((lc2 & 7) << 1)) & 15) << 4)) =
        *(const uint4*)(Rb + (size_t)(c0 + lc2) * 768 + c2 * 16);
    #pragma unroll
    for (int i = 0; i < 2; i++){
      int idx = i * 256 + t;
      int row = idx >> 5, c16 = idx & 31;
      *(uint4*)(h0s + row * 544 + c16 * 16) =
          *(const uint4*)(Rb + (size_t)(c0 + row) * 768 + 256 + c16 * 16);
    }
  }
  __syncthreads();

  // P2: dots + softmax, all 256 threads: t = [px(4b)][n(2b)][cq(2b)]
  float myatt;
  {
    const int px = t >> 4, n = (t >> 2) & 3, cq2 = t & 3;
    const int fr = px * 4 + n;
    float d = 0.f;
    #pragma unroll
    for (int g = 0; g < 4; g++){
      int c = cq2 * 4 + g;
      bf16x8 rv = *(const bf16x8*)(rs  + px * 256 + (((c ^ ((px & 7) << 1)) & 15) << 4));
      bf16x8 fv = *(const bf16x8*)(x0s + fr * 256 + (((c ^ ((fr & 7) << 1)) & 15) << 4));
      #pragma unroll
      for (int e = 0; e < 8; e++) d += (float)rv[e] * (float)fv[e];
    }
    d += __shfl_xor(d, 1); d += __shfl_xor(d, 2);
    float s4 = d + __shfl_xor(d, 4); s4 += __shfl_xor(s4, 8);
    float irr = 0.5f * s4 - d;
    float mx = fmaxf(irr, __shfl_xor(irr, 4)); mx = fmaxf(mx, __shfl_xor(mx, 8));
    float e1 = __expf(irr - mx);
    float den = e1 + __shfl_xor(e1, 4); den += __shfl_xor(den, 8);
    myatt = e1 / den;
  }
  // no barrier: rs row px / x0s quarters / att all wave-local for P3

  // P3: y = sum_n att*x0_n -> rs bf16 swizzled
  {
    const int px = t >> 4, cp = t & 15;
    float o[8];
    #pragma unroll
    for (int e = 0; e < 8; e++) o[e] = 0.f;
    #pragma unroll
    for (int n = 0; n < 4; n++){
      float a = __shfl(myatt, (t & 48) | (n << 2));
      int fr = px * 4 + n;
      bf16x8 fv = *(const bf16x8*)(x0s + fr * 256 + (((cp ^ ((fr & 7) << 1)) & 15) << 4));
      #pragma unroll
      for (int e = 0; e < 8; e++) o[e] += a * (float)fv[e];
    }
    uint4 wv_;
    wv_.x = (u32)f2bf(o[0]) | ((u32)f2bf(o[1]) << 16);
    wv_.y = (u32)f2bf(o[2]) | ((u32)f2bf(o[3]) << 16);
    wv_.z = (u32)f2bf(o[4]) | ((u32)f2bf(o[5]) << 16);
    wv_.w = (u32)f2bf(o[6]) | ((u32)f2bf(o[7]) << 16);
    *(uint4*)(rs + px * 256 + (((cp ^ ((px & 7) << 1)) & 15) << 4)) = wv_;
  }
  __syncthreads();

  // P4: p0 = Wdvc @ y + h0 (b3 pre-folded) via MFMA -> fp32 LDS stage
  {
    bf16x8 af[4];
    #pragma unroll
    for (int kt = 0; kt < 4; kt++){
      int chunk = kt * 4 + lg;
      af[kt] = *(const bf16x8*)(rs + lr * 256 + (((chunk ^ ((lr & 7) << 1)) & 15) << 4));
    }
    #pragma unroll
    for (int jj = 0; jj < 4; jj++){
      int jn = wid * 4 + jj;
      f32x4 acc = (f32x4){0.f, 0.f, 0.f, 0.f};
      #pragma unroll
      for (int kt = 0; kt < 4; kt++){
        bf16x8 bfr = *(const bf16x8*)(wdvi + (jn * 16 + lr) * 256 + (kt * 4 + lg) * 16);
        acc = __builtin_amdgcn_mfma_f32_16x16x32_bf16(af[kt], bfr, acc, 0, 0, 0);
      }
      int oc = jn * 16 + lr;
      if (oc < 255){
        int a = oc / 85, o = oc - a * 85;
        #pragma unroll
        for (int ri = 0; ri < 4; ri++){
          int px = lg * 4 + ri;
          float v = acc[ri] + bf2f(*(const u16*)(h0s + px * 544 + oc * 2));
          stg[a * 1360 + px * 85 + o] = v;
        }
      }
    }
  }
  __syncthreads();

  // P5: coalesced float4 p0 store (3 contiguous 5440B segments)
  {
    #pragma unroll
    for (int it = 0; it < 4; it++){
      int idx = it * 256 + t;
      if (idx < 1020){
        int a = idx / 340, r4 = idx - a * 340;
        *(float4*)(out + ((size_t)(b * 3 + a) * 6400 + pr) * 85 + r4 * 4) =
            *(const float4*)(stg + a * 1360 + r4 * 4);
      }
    }
  }
}

extern "C" void kernel_launch(void* const* d_in, const int* in_sizes, int n_in,
                              void* d_out, int out_size, void* d_ws, size_t ws_size,
                              hipStream_t stream)
{
  (void)in_sizes; (void)n_in; (void)out_size; (void)ws_size;
  const float* x0  = (const float*)d_in[0];
  const float* x1  = (const float*)d_in[1];
  const float* x2  = (const float*)d_in[2];
  const float* x3  = (const float*)d_in[3];
  const float* wc1 = (const float*)d_in[4];  const float* bc1 = (const float*)d_in[5];
  const float* wc2 = (const float*)d_in[6];  const float* bc2 = (const float*)d_in[7];
  const float* wq  = (const float*)d_in[8];  const float* bq  = (const float*)d_in[9];
  const float* wk  = (const float*)d_in[10];
  const float* wv  = (const float*)d_in[12]; const float* bv  = (const float*)d_in[13];
  const float* wdt = (const float*)d_in[14]; const float* bdt = (const float*)d_in[15];
  const float* wm0 = (const float*)d_in[16]; const float* bm0 = (const float*)d_in[17];
  const float* wm1 = (const float*)d_in[18]; const float* bm1 = (const float*)d_in[19];
  char* ws = (char*)d_ws;
  float* out = (float*)d_out;

  prepA_k<<<384, 256, 0, stream>>>(wq, bq, wc2, bc2, wk, wv, wc1, bc1, bv, ws);
  prep2_k<<<2052, 256, 0, stream>>>(wc2, wdt, bdt, wm0, bm0, wm1, bm1, bc2, ws);
  // combined: p2 (0-49) | p1 (50-249) | R = A1@x1+c1 (250-1449)
  gemms_k<<<1450, 256, 0, stream>>>(x1, x2, x3, ws, out);
  // fused dots/softmax/y/p0
  clla_k<<<3200, 256, 0, stream>>>(x0, ws, out);
}